// Round 5
// baseline (221.450 us; speedup 1.0000x reference)
//
#include <hip/hip_runtime.h>
#include <math.h>

// Reverse cumulative max (suffix max) along last dim.
// x: (8,1,2048,2048) fp32 -> 16384 rows of W=2048.
//
// Round 5: round 4 (nontemporal loads AND stores, one-shot waves) was the
// first change to move the 2.47 TB/s wall -> kernel dropped below the
// fillBuffer dispatches (<79.7us, ~68us implied). LLC-thrash theory
// confirmed: in+out working set == 256 MiB == Infinity Cache; bypassing
// allocation on both streams unjams it. Remaining gap to the ~45us
// roofline: NT loads pay full HBM latency (~900cy) and the one-shot shape
// (burst -> vmcnt(0) -> serial scan -> store -> die) leaves the pipe idle
// during scan+store. Fix: 2 rows/wave register ping-pong (load b; scan/store
// a under b's loads). 2048 blocks = 8192 waves = full wave-slot capacity.

#define ROW_W 2048
#define LANES 64
#define CHUNKS 8               // float4 per lane per row (8*64*4 = 2048)
#define WAVES_PER_BLOCK 4
#define ROWS_PER_WAVE 2

typedef float nf4 __attribute__((ext_vector_type(4)));

__global__ __launch_bounds__(256) void suffix_max_kernel(
    const float* __restrict__ x, float* __restrict__ out, int nrows) {
  const int lane = threadIdx.x & 63;
  const int wid  = (blockIdx.x << 2) | (threadIdx.x >> 6);  // global wave id
  const int nw   = gridDim.x << 2;                          // total waves

  auto loadrow = [&](nf4 (&v)[CHUNKS], int row) {
    if (row < nrows) {
      const nf4* __restrict__ p = (const nf4*)(x + (size_t)row * ROW_W) + lane;
#pragma unroll
      for (int k = 0; k < CHUNKS; ++k)
        v[k] = __builtin_nontemporal_load(&p[k * LANES]);
    }
  };

  auto process = [&](nf4 (&v)[CHUNKS], int row) {
    if (row >= nrows) return;
    // 1) suffix max inside each float4 (right-to-left).
    float inc[CHUNKS];
#pragma unroll
    for (int k = 0; k < CHUNKS; ++k) {
      v[k].z = fmaxf(v[k].z, v[k].w);
      v[k].y = fmaxf(v[k].y, v[k].z);
      v[k].x = fmaxf(v[k].x, v[k].y);
      inc[k] = v[k].x;
    }
    // 2) eight independent 64-lane suffix scans (fmaxf idempotent, no guards).
#pragma unroll
    for (int off = 1; off < LANES; off <<= 1) {
#pragma unroll
      for (int k = 0; k < CHUNKS; ++k) {
        float o = __shfl_down(inc[k], off, LANES);
        inc[k] = fmaxf(inc[k], o);
      }
    }
    float tot[CHUNKS], excl[CHUNKS];
#pragma unroll
    for (int k = 0; k < CHUNKS; ++k) tot[k] = __shfl(inc[k], 0, LANES);
#pragma unroll
    for (int k = 0; k < CHUNKS; ++k) {
      float e = __shfl_down(inc[k], 1, LANES);
      excl[k] = (lane == 63) ? -INFINITY : e;
    }
    // 3) serial fold across chunks, right to left.
    float tail = -INFINITY;
#pragma unroll
    for (int k = CHUNKS - 1; k >= 0; --k) {
      const float e = fmaxf(excl[k], tail);
      v[k].x = fmaxf(v[k].x, e);
      v[k].y = fmaxf(v[k].y, e);
      v[k].z = fmaxf(v[k].z, e);
      v[k].w = fmaxf(v[k].w, e);
      tail = fmaxf(tail, tot[k]);
    }
    // Nontemporal coalesced stores: 1 KiB per instruction.
    nf4* __restrict__ q = (nf4*)(out + (size_t)row * ROW_W) + lane;
#pragma unroll
    for (int k = 0; k < CHUNKS; ++k)
      __builtin_nontemporal_store(v[k], &q[k * LANES]);
  };

  // 2-deep register ping-pong: row wid and row wid+nw.
  nf4 a[CHUNKS], b[CHUNKS];
  loadrow(a, wid);
  loadrow(b, wid + nw);
  process(a, wid);          // scan+store row a under row b's in-flight loads
  process(b, wid + nw);
}

extern "C" void kernel_launch(void* const* d_in, const int* in_sizes, int n_in,
                              void* d_out, int out_size, void* d_ws, size_t ws_size,
                              hipStream_t stream) {
  const float* x = (const float*)d_in[0];
  float* out = (float*)d_out;
  const int nrows = out_size / ROW_W;  // 16384
  // 4 waves/block * 2 rows/wave = 8 rows per block -> 2048 blocks = 8192 waves.
  const int blocks = (nrows + WAVES_PER_BLOCK * ROWS_PER_WAVE - 1) /
                     (WAVES_PER_BLOCK * ROWS_PER_WAVE);
  suffix_max_kernel<<<blocks, 256, 0, stream>>>(x, out, nrows);
}

// Round 6
// 220.740 us; speedup vs baseline: 1.0032x; 1.0032x over previous
//
#include <hip/hip_runtime.h>
#include <math.h>

// Reverse cumulative max (suffix max) along last dim.
// x: (8,1,2048,2048) fp32 -> 16384 rows of W=2048. One wave per row.
//
// Round 6: completing the {load,store} x {alloc,NT} matrix.
//   alloc/alloc = 81us, alloc-load/NT-store = 81us, NT/NT = ~76us.
// This round: NT loads + ALLOCATING stores. Model: the re-poison fill
// leaves LLC full of CLEAN lines (its WRITE_SIZE == footprint, so it wrote
// through). NT reads claim no LLC capacity; the 128 MiB output stream fits
// in the 256 MiB LLC entirely, so store-allocated dirty lines can sit
// (R0-R3's in-window writebacks happened because read+write allocation
// demanded 256 MiB >= LLC). Expect: FETCH ~128 MiB, in-window WRITE_SIZE
// << 128 MiB, kernel -> 30-55us. If neutral, mixed-stream wall = roofline.

#define ROW_W 2048
#define LANES 64
#define CHUNKS 8               // float4 per lane (8*64*4 = 2048)
#define WAVES_PER_BLOCK 4

typedef float nf4 __attribute__((ext_vector_type(4)));

__global__ __launch_bounds__(256) void suffix_max_kernel(
    const float* __restrict__ x, float* __restrict__ out, int nrows) {
  const int lane = threadIdx.x & 63;
  const int row  = blockIdx.x * WAVES_PER_BLOCK + (threadIdx.x >> 6);
  if (row >= nrows) return;

  const nf4* __restrict__ p = (const nf4*)(x   + (size_t)row * ROW_W) + lane;
  nf4* __restrict__       q = (nf4*)      (out + (size_t)row * ROW_W) + lane;

  // Nontemporal coalesced loads: instr k reads float4s [64k,64k+64) -> 1 KiB.
  nf4 v[CHUNKS];
#pragma unroll
  for (int k = 0; k < CHUNKS; ++k)
    v[k] = __builtin_nontemporal_load(&p[k * LANES]);

  // 1) Suffix max inside each float4 (right-to-left).
  float inc[CHUNKS];
#pragma unroll
  for (int k = 0; k < CHUNKS; ++k) {
    v[k].z = fmaxf(v[k].z, v[k].w);
    v[k].y = fmaxf(v[k].y, v[k].z);
    v[k].x = fmaxf(v[k].x, v[k].y);
    inc[k] = v[k].x;
  }

  // 2) Eight independent 64-lane suffix scans (fmaxf idempotent -> no guards).
#pragma unroll
  for (int off = 1; off < LANES; off <<= 1) {
#pragma unroll
    for (int k = 0; k < CHUNKS; ++k) {
      float o = __shfl_down(inc[k], off, LANES);
      inc[k] = fmaxf(inc[k], o);
    }
  }

  float tot[CHUNKS], excl[CHUNKS];
#pragma unroll
  for (int k = 0; k < CHUNKS; ++k) tot[k] = __shfl(inc[k], 0, LANES);
#pragma unroll
  for (int k = 0; k < CHUNKS; ++k) {
    float e = __shfl_down(inc[k], 1, LANES);
    excl[k] = (lane == 63) ? -INFINITY : e;
  }

  // 3) Serial fold across chunks, right to left.
  float tail = -INFINITY;
#pragma unroll
  for (int k = CHUNKS - 1; k >= 0; --k) {
    const float e = fmaxf(excl[k], tail);
    v[k].x = fmaxf(v[k].x, e);
    v[k].y = fmaxf(v[k].y, e);
    v[k].z = fmaxf(v[k].z, e);
    v[k].w = fmaxf(v[k].w, e);
    tail = fmaxf(tail, tot[k]);
  }

  // ALLOCATING coalesced stores: absorbed by LLC (output fits in 256 MiB).
#pragma unroll
  for (int k = 0; k < CHUNKS; ++k)
    q[k * LANES] = v[k];
}

extern "C" void kernel_launch(void* const* d_in, const int* in_sizes, int n_in,
                              void* d_out, int out_size, void* d_ws, size_t ws_size,
                              hipStream_t stream) {
  const float* x = (const float*)d_in[0];
  float* out = (float*)d_out;
  const int nrows = out_size / ROW_W;  // 16384
  const int blocks = (nrows + WAVES_PER_BLOCK - 1) / WAVES_PER_BLOCK;
  suffix_max_kernel<<<blocks, 256, 0, stream>>>(x, out, nrows);
}